// Round 15
// baseline (1764.557 us; speedup 1.0000x reference)
//
#include <hip/hip_runtime.h>

// RandomWalkPositionalEncoding: out[i, k-1] = diag(P^k)[i], k=1..10, P = A/(deg+1e-8)
// S = D^-1/2 A D^-1/2 (symmetric): diag(P^k) = diag(S^k);
//   k=1 from self-loop bit; k=2 analytic: dinv_r^2 * sum_{c in N(r)} dinv_c^2;
//   k=2m+1 = <W_m, W_{m+1}>, k=2m+2 = ||W_{m+1}||^2 over rows, W_m = S^m E.
// CSR packed u32 = col | f16(S_rc)<<16 -> inner loop is v_fma_mix_f32 (4-deep
// unroll, 32 VGPR, ~76% occupancy). Plain panel stores (R14: NT stores bypass L3
// and starve the next dispatch's gathers). spmm is at ~97% of the L2-BW roofline:
// logical gather = nnz*B*2B = 4.3 GB/dispatch / 34.5 TB/s = 124 us vs 128.5 meas.
// [R15 = R14 + direct atomicAdd epilogue]: spmm's block column-sums go straight
// into out (256 adds/slot across grid) — deletes reduce_final dispatches and the
// partial buffer (workspace may now fit B=8192 -> single pass).
// SpMM: 128-col groups L2-pinned per XCD (blockIdx&7); rows degree-sorted.

#define NN 8192
#define NWORDS 256            // NN/32 u32 words per bitmap row
#define EMB 32
#define GCOLS 128             // columns per group (slice = NN*GCOLS*2 = 2 MB)
#define TPR 16                // threads per row (16 x 8 cols = 128)
#define RPB 32                // rows per block (512 threads)
#define NRB (NN / RPB)        // row-blocks = 256

typedef _Float16 half8 __attribute__((ext_vector_type(8)));
typedef _Float16 half2t __attribute__((ext_vector_type(2)));
typedef unsigned int u32x4 __attribute__((ext_vector_type(4)));

__global__ void scatter_edges(const int* __restrict__ ei, unsigned* __restrict__ bm, int nE) {
    int e = blockIdx.x * blockDim.x + threadIdx.x;
    if (e >= nE) return;
    int r = ei[e];
    int c = ei[nE + e];
    atomicOr(&bm[(size_t)r * NWORDS + (c >> 5)], 1u << (c & 31));
    atomicOr(&bm[(size_t)c * NWORDS + (r >> 5)], 1u << (r & 31));
}

// one wave per row: popcount 256 words, write degree, dinv_sqrt, and k=1 diagonal.
__global__ void degree_kernel(const unsigned* __restrict__ bm, int* __restrict__ deg,
                              float* __restrict__ dinv, float* __restrict__ out) {
    int lane = threadIdx.x & 63;
    int r = blockIdx.x * (blockDim.x >> 6) + (threadIdx.x >> 6);
    const unsigned* row = bm + (size_t)r * NWORDS;
    uint4 w = *(const uint4*)(row + lane * 4);
    int cnt = __popc(w.x) + __popc(w.y) + __popc(w.z) + __popc(w.w);
    for (int d = 32; d; d >>= 1) cnt += __shfl_down(cnt, d);
    if (lane == 0) {
        deg[r] = cnt;
        float dt = (float)cnt + 1e-8f;       // matches reference f32 rounding
        dinv[r] = rsqrtf(dt);
        unsigned selfw = row[r >> 5];
        out[(size_t)r * EMB] = ((selfw >> (r & 31)) & 1u) ? (1.0f / dt) : 0.0f;
    }
}

// single-block exclusive scan of 8192 degrees -> rowptr[0..8192]
__global__ void scan_kernel(const int* __restrict__ deg, int* __restrict__ rowptr) {
    __shared__ int wsum[4];
    __shared__ int base;
    int tid = threadIdx.x;          // 256 threads
    int lane = tid & 63, wid = tid >> 6;
    if (tid == 0) base = 0;
    __syncthreads();
    for (int ch = 0; ch < NN / 256; ++ch) {
        int idx = ch * 256 + tid;
        int v = deg[idx];
        int s = v;
#pragma unroll
        for (int d = 1; d < 64; d <<= 1) {
            int t = __shfl_up(s, d);
            if (lane >= d) s += t;
        }
        if (lane == 63) wsum[wid] = s;
        __syncthreads();
        int ofs = base;
        for (int w = 0; w < wid; ++w) ofs += wsum[w];
        rowptr[idx] = ofs + s - v;
        int tot = wsum[0] + wsum[1] + wsum[2] + wsum[3];
        __syncthreads();
        if (tid == 0) base += tot;
        __syncthreads();
    }
    if (tid == 0) rowptr[NN] = base;
}

// thread per row: bitmap row -> packed u32 (col | f16(dinv_r*dinv_c)<<16)
__global__ void fill_cpk(const unsigned* __restrict__ bm, const int* __restrict__ rowptr,
                         const float* __restrict__ dinv, unsigned* __restrict__ cpk) {
    int r = blockIdx.x * blockDim.x + threadIdx.x;
    if (r >= NN) return;
    int p = rowptr[r];
    float dr = dinv[r];
    const unsigned* row = bm + (size_t)r * NWORDS;
    for (int w = 0; w < NWORDS; ++w) {
        unsigned bits = row[w];
        while (bits) {
            int b = __ffs(bits) - 1;
            bits &= bits - 1;
            int c = w * 32 + b;
            _Float16 vh = (_Float16)(dr * dinv[c]);
            unsigned short hv = __builtin_bit_cast(unsigned short, vh);
            cpk[p++] = (unsigned)c | ((unsigned)hv << 16);
        }
    }
}

// diag(S^2)[r] = dinv_r^2 * sum_{c in N(r)} dinv_c^2   (exact, f32)
__global__ void diag2_kernel(const int* __restrict__ rowptr, const unsigned* __restrict__ cpk,
                             const float* __restrict__ dinv, float* __restrict__ out) {
    int r = blockIdx.x * blockDim.x + threadIdx.x;
    if (r >= NN) return;
    int s = rowptr[r], e = rowptr[r + 1];
    float acc = 0.f;
    for (int p = s; p < e; ++p) {
        float d = dinv[cpk[p] & 0xffffu];
        acc += d * d;
    }
    float dr = dinv[r];
    out[(size_t)r * EMB + 1] = dr * dr * acc;
}

// ---- degree counting sort: histogram -> scan -> scatter (perf-only permutation) ----
__global__ void hist_kernel(const int* __restrict__ deg, int* __restrict__ hist) {
    int r = blockIdx.x * 256 + threadIdx.x;
    if (r < NN) atomicAdd(&hist[min(deg[r], 255)], 1);
}

__global__ void histscan_kernel(const int* __restrict__ hist, int* __restrict__ binofs) {
    __shared__ int wsum[4];
    int tid = threadIdx.x;            // 256 threads
    int lane = tid & 63, wid = tid >> 6;
    int v = hist[tid];
    int s = v;
#pragma unroll
    for (int d = 1; d < 64; d <<= 1) {
        int t = __shfl_up(s, d);
        if (lane >= d) s += t;
    }
    if (lane == 63) wsum[wid] = s;
    __syncthreads();
    int ofs = 0;
    for (int w = 0; w < wid; ++w) ofs += wsum[w];
    binofs[tid] = ofs + s - v;
}

__global__ void permute_kernel(const int* __restrict__ deg, int* __restrict__ binofs,
                               int* __restrict__ perm) {
    int r = blockIdx.x * 256 + threadIdx.x;
    if (r < NN) {
        int pos = atomicAdd(&binofs[min(deg[r], 255)], 1);
        perm[pos] = r;
    }
}

// block per row: zero the row then scatter S values (fused memset+init)
__global__ void init_w1(const int* __restrict__ rowptr, const unsigned* __restrict__ cpk,
                        _Float16* __restrict__ W1, int c0, int B) {
    int r = blockIdx.x;
    _Float16* wr = W1 + (size_t)r * B;
    half8 z = {0, 0, 0, 0, 0, 0, 0, 0};
    for (int i = threadIdx.x; i < (B >> 3); i += 256) ((half8*)wr)[i] = z;
    __syncthreads();
    int s = rowptr[r], e = rowptr[r + 1];
    for (int p = s + (int)threadIdx.x; p < e; p += 256) {
        unsigned w = cpk[p];
        unsigned j = (w & 0xffffu) - (unsigned)c0;
        if (j < (unsigned)B) ((unsigned short*)wr)[j] = (unsigned short)(w >> 16);
    }
}

// Wnxt[r, grp cols] = sum_{c in N(r)} S_rc * Win[c, grp cols]  (v_fma_mix, u32 saddr offs).
// Rows taken via degree-sorted perm -> all rows in a block have ~equal nnz.
// Fused: dot_j += W_m[r,j]*Wnxt[r,j], nrm_j += Wnxt[r,j]^2; block sums atomicAdd
// straight into out (slots tdot/tnorm, pre-zeroed) — no partial buffer.
__global__ __launch_bounds__(512) void
spmm_fused(const int* __restrict__ rowptr, const unsigned* __restrict__ cpk,
           const int* __restrict__ perm, const _Float16* __restrict__ Win,
           _Float16* __restrict__ Wout, float* __restrict__ out,
           int bsh /*log2(B)*/, int SUBS, int c0, int tdot, int tnorm) {
    int i = blockIdx.x;
    int xcd = i & 7;
    int q = i >> 3;
    int sub = q / NRB;
    int rblk = q - sub * NRB;
    int grp = xcd * SUBS + sub;
    int tid = threadIdx.x;
    int lane = tid & (TPR - 1);
    int r = perm[rblk * RPB + (tid >> 4)];
    int j = grp * GCOLS + lane * 8;
    const char* Wc = (const char*)Win;
    unsigned jb = (unsigned)(j * 2);
    int sh = bsh + 1;
    int p = rowptr[r], e = rowptr[r + 1];
    float acc[8] = {0.f, 0.f, 0.f, 0.f, 0.f, 0.f, 0.f, 0.f};
    for (; p + 4 <= e; p += 4) {
        unsigned w0 = cpk[p], w1 = cpk[p + 1], w2 = cpk[p + 2], w3 = cpk[p + 3];
        half8 s0 = *(const half8*)(Wc + (((w0 & 0xffffu) << sh) + jb));
        half8 s1 = *(const half8*)(Wc + (((w1 & 0xffffu) << sh) + jb));
        half8 s2 = *(const half8*)(Wc + (((w2 & 0xffffu) << sh) + jb));
        half8 s3 = *(const half8*)(Wc + (((w3 & 0xffffu) << sh) + jb));
        half2t v0 = __builtin_bit_cast(half2t, w0);
        half2t v1 = __builtin_bit_cast(half2t, w1);
        half2t v2 = __builtin_bit_cast(half2t, w2);
        half2t v3 = __builtin_bit_cast(half2t, w3);
#pragma unroll
        for (int k = 0; k < 8; ++k) {
            acc[k] = fmaf((float)s0[k], (float)v0[1], acc[k]);   // v_fma_mix_f32
            acc[k] = fmaf((float)s1[k], (float)v1[1], acc[k]);
            acc[k] = fmaf((float)s2[k], (float)v2[1], acc[k]);
            acc[k] = fmaf((float)s3[k], (float)v3[1], acc[k]);
        }
    }
    for (; p < e; ++p) {
        unsigned w0 = cpk[p];
        half8 s0 = *(const half8*)(Wc + (((w0 & 0xffffu) << sh) + jb));
        half2t v0 = __builtin_bit_cast(half2t, w0);
#pragma unroll
        for (int k = 0; k < 8; ++k) acc[k] = fmaf((float)s0[k], (float)v0[1], acc[k]);
    }
    union { half8 h; u32x4 u; } o;
#pragma unroll
    for (int k = 0; k < 8; ++k) o.h[k] = (_Float16)acc[k];
    *(u32x4*)(Wout + (((size_t)r << bsh)) + j) = o.u;        // plain store (L3-resident next)

    // fused reductions: a = W_m[r, j..j+8] is an L2-hit inside the resident slice
    half8 a = *(const half8*)(Win + ((size_t)r << bsh) + j);
    float d[8], n[8];
#pragma unroll
    for (int k = 0; k < 8; ++k) {
        float b = acc[k];
        d[k] = (float)a[k] * b;
        n[k] = b * b;
    }
#pragma unroll
    for (int k = 0; k < 8; ++k) {            // reduce the 4 rows within a wave
        d[k] += __shfl_xor(d[k], 16);
        d[k] += __shfl_xor(d[k], 32);
        n[k] += __shfl_xor(n[k], 16);
        n[k] += __shfl_xor(n[k], 32);
    }
    __shared__ float red[8][2][8][17];       // [wave][dot/nrm][k][lane16] (+1 pad: no conflicts)
    int wv = tid >> 6;
    int l64 = tid & 63;
    if (l64 < 16) {
#pragma unroll
        for (int k = 0; k < 8; ++k) {
            red[wv][0][k][l64] = d[k];
            red[wv][1][k][l64] = n[k];
        }
    }
    __syncthreads();
    if (tid < 2 * GCOLS) {
        int which = tid >> 7;
        int col = tid & (GCOLS - 1);         // col = l16*8 + k
        float s = 0.f;
#pragma unroll
        for (int w = 0; w < 8; ++w) s += red[w][which][col & 7][col >> 3];
        int gcol = c0 + grp * GCOLS + col;
        atomicAdd(out + (size_t)gcol * EMB + (which ? tnorm : tdot), s);
    }
}

extern "C" void kernel_launch(void* const* d_in, const int* in_sizes, int n_in,
                              void* d_out, int out_size, void* d_ws, size_t ws_size,
                              hipStream_t stream) {
    const int* ei = (const int*)d_in[1];     // edge_index [2, nE]
    int nE = in_sizes[1] / 2;                // 131072
    float* out = (float*)d_out;

    char* ws = (char*)d_ws;
    size_t off = 0;
    auto alloc = [&](size_t bytes) -> void* {
        void* p = ws + off;
        off = (off + bytes + 255) & ~(size_t)255;
        return p;
    };
    unsigned* bm  = (unsigned*)alloc((size_t)NN * NWORDS * 4);   // 8 MB bitmap
    int*      deg = (int*)alloc((size_t)NN * 4);
    float*   dinv = (float*)alloc((size_t)NN * 4);
    int*   rowptr = (int*)alloc((size_t)(NN + 1) * 4);
    size_t maxnnz = 2 * (size_t)nE;
    unsigned* cpk = (unsigned*)alloc(maxnnz * 4);
    int*     hist = (int*)alloc(256 * 4);
    int*   binofs = (int*)alloc(256 * 4);
    int*     perm = (int*)alloc((size_t)NN * 4);
    size_t fixed = off;

    // column width: prefer one pass (B=8192); panel pair must fit workspace.
    int B = 8192, bsh = 13;
    while (B > 2048 && fixed + 2 * (size_t)NN * B * 2 > ws_size) {
        B >>= 1; bsh--;
    }
    _Float16* Wa = (_Float16*)alloc((size_t)NN * B * 2);
    _Float16* Wb = (_Float16*)alloc((size_t)NN * B * 2);
    int SUBS = (B / GCOLS) / 8;              // col-group slices per XCD

    (void)hipMemsetAsync(d_out, 0, (size_t)out_size * 4, stream);
    (void)hipMemsetAsync(bm, 0, (size_t)NN * NWORDS * 4, stream);
    (void)hipMemsetAsync(hist, 0, 256 * 4, stream);

    scatter_edges<<<(nE + 255) / 256, 256, 0, stream>>>(ei, bm, nE);
    degree_kernel<<<NN / 4, 256, 0, stream>>>(bm, deg, dinv, out);
    scan_kernel<<<1, 256, 0, stream>>>(deg, rowptr);
    fill_cpk<<<NN / 256, 256, 0, stream>>>(bm, rowptr, dinv, cpk);
    diag2_kernel<<<NN / 256, 256, 0, stream>>>(rowptr, cpk, dinv, out);
    hist_kernel<<<NN / 256, 256, 0, stream>>>(deg, hist);
    histscan_kernel<<<1, 256, 0, stream>>>(hist, binofs);
    permute_kernel<<<NN / 256, 256, 0, stream>>>(deg, binofs, perm);

    dim3 spmm_grid(8 * SUBS * NRB);

    for (int c0 = 0; c0 < NN; c0 += B) {
        init_w1<<<NN, 256, 0, stream>>>(rowptr, cpk, Wa, c0, B);
        _Float16* cur = Wa;
        _Float16* nxt = Wb;
        for (int m = 1; m <= 4; ++m) {
            // k=2m+1 (slot 2m): <W_m,W_{m+1}>;  k=2m+2 (slot 2m+1): ||W_{m+1}||^2
            spmm_fused<<<spmm_grid, 512, 0, stream>>>(rowptr, cpk, perm, cur, nxt,
                                                      out, bsh, SUBS, c0,
                                                      2 * m, 2 * m + 1);
            _Float16* t = cur; cur = nxt; nxt = t;
        }
    }
}

// Round 16
// 1287.549 us; speedup vs baseline: 1.3705x; 1.3705x over previous
//
#include <hip/hip_runtime.h>

// RandomWalkPositionalEncoding: out[i, k-1] = diag(P^k)[i], k=1..10, P = A/(deg+1e-8)
// S = D^-1/2 A D^-1/2 (symmetric): diag(P^k) = diag(S^k);
//   k=1 from self-loop bit; k=2 analytic: dinv_r^2 * sum_{c in N(r)} dinv_c^2;
//   k=2m+1 = <W_m, W_{m+1}>, k=2m+2 = ||W_{m+1}||^2 over rows, W_m = S^m E.
// CSR packed u32 = col | f16(S_rc)<<16 -> inner loop is v_fma_mix_f32 (4-deep
// unroll, 32 VGPR, ~76% occupancy).
// [R16 = verbatim R14 revert — best passing kernel, 1288 us.] Ablation ledger:
//   pad stride (R7/R8): -20% | quad-dwordx4 (R9/R10): broken | 8-unroll (R12):
//   -12% (52 VGPR occupancy cliff) | GCOLS=64 (R13): -10% (2x cpk re-reads) |
//   plain panel store (R14): +3% kept | direct-atomic epilogue (R15): -37%
//   (every atomicAdd = 64B HBM write-through; WRITE_SIZE 2M x 64B exact match).
// spmm serves 2.1 GB logical gather/dispatch at ~16.4 TB/s effective L2+L3
// random-gather rate — no saturated pipe remains (VALU 56%, HBM 30%, occ 75%).
// SpMM: 128-col groups L2-pinned per XCD (blockIdx&7); rows degree-sorted;
// dot/norm fused -> NT partials -> parallel reduce_final with atomicAdd.

#define NN 8192
#define NWORDS 256            // NN/32 u32 words per bitmap row
#define EMB 32
#define GCOLS 128             // columns per group (slice = NN*GCOLS*2 = 2 MB)
#define TPR 16                // threads per row (16 x 8 cols = 128)
#define RPB 32                // rows per block (512 threads)
#define NRB (NN / RPB)        // row-blocks = 256

typedef _Float16 half8 __attribute__((ext_vector_type(8)));
typedef _Float16 half2t __attribute__((ext_vector_type(2)));
typedef unsigned int u32x4 __attribute__((ext_vector_type(4)));

__global__ void scatter_edges(const int* __restrict__ ei, unsigned* __restrict__ bm, int nE) {
    int e = blockIdx.x * blockDim.x + threadIdx.x;
    if (e >= nE) return;
    int r = ei[e];
    int c = ei[nE + e];
    atomicOr(&bm[(size_t)r * NWORDS + (c >> 5)], 1u << (c & 31));
    atomicOr(&bm[(size_t)c * NWORDS + (r >> 5)], 1u << (r & 31));
}

// one wave per row: popcount 256 words, write degree, dinv_sqrt, and k=1 diagonal.
__global__ void degree_kernel(const unsigned* __restrict__ bm, int* __restrict__ deg,
                              float* __restrict__ dinv, float* __restrict__ out) {
    int lane = threadIdx.x & 63;
    int r = blockIdx.x * (blockDim.x >> 6) + (threadIdx.x >> 6);
    const unsigned* row = bm + (size_t)r * NWORDS;
    uint4 w = *(const uint4*)(row + lane * 4);
    int cnt = __popc(w.x) + __popc(w.y) + __popc(w.z) + __popc(w.w);
    for (int d = 32; d; d >>= 1) cnt += __shfl_down(cnt, d);
    if (lane == 0) {
        deg[r] = cnt;
        float dt = (float)cnt + 1e-8f;       // matches reference f32 rounding
        dinv[r] = rsqrtf(dt);
        unsigned selfw = row[r >> 5];
        out[(size_t)r * EMB] = ((selfw >> (r & 31)) & 1u) ? (1.0f / dt) : 0.0f;
    }
}

// single-block exclusive scan of 8192 degrees -> rowptr[0..8192]
__global__ void scan_kernel(const int* __restrict__ deg, int* __restrict__ rowptr) {
    __shared__ int wsum[4];
    __shared__ int base;
    int tid = threadIdx.x;          // 256 threads
    int lane = tid & 63, wid = tid >> 6;
    if (tid == 0) base = 0;
    __syncthreads();
    for (int ch = 0; ch < NN / 256; ++ch) {
        int idx = ch * 256 + tid;
        int v = deg[idx];
        int s = v;
#pragma unroll
        for (int d = 1; d < 64; d <<= 1) {
            int t = __shfl_up(s, d);
            if (lane >= d) s += t;
        }
        if (lane == 63) wsum[wid] = s;
        __syncthreads();
        int ofs = base;
        for (int w = 0; w < wid; ++w) ofs += wsum[w];
        rowptr[idx] = ofs + s - v;
        int tot = wsum[0] + wsum[1] + wsum[2] + wsum[3];
        __syncthreads();
        if (tid == 0) base += tot;
        __syncthreads();
    }
    if (tid == 0) rowptr[NN] = base;
}

// thread per row: bitmap row -> packed u32 (col | f16(dinv_r*dinv_c)<<16)
__global__ void fill_cpk(const unsigned* __restrict__ bm, const int* __restrict__ rowptr,
                         const float* __restrict__ dinv, unsigned* __restrict__ cpk) {
    int r = blockIdx.x * blockDim.x + threadIdx.x;
    if (r >= NN) return;
    int p = rowptr[r];
    float dr = dinv[r];
    const unsigned* row = bm + (size_t)r * NWORDS;
    for (int w = 0; w < NWORDS; ++w) {
        unsigned bits = row[w];
        while (bits) {
            int b = __ffs(bits) - 1;
            bits &= bits - 1;
            int c = w * 32 + b;
            _Float16 vh = (_Float16)(dr * dinv[c]);
            unsigned short hv = __builtin_bit_cast(unsigned short, vh);
            cpk[p++] = (unsigned)c | ((unsigned)hv << 16);
        }
    }
}

// diag(S^2)[r] = dinv_r^2 * sum_{c in N(r)} dinv_c^2   (exact, f32)
__global__ void diag2_kernel(const int* __restrict__ rowptr, const unsigned* __restrict__ cpk,
                             const float* __restrict__ dinv, float* __restrict__ out) {
    int r = blockIdx.x * blockDim.x + threadIdx.x;
    if (r >= NN) return;
    int s = rowptr[r], e = rowptr[r + 1];
    float acc = 0.f;
    for (int p = s; p < e; ++p) {
        float d = dinv[cpk[p] & 0xffffu];
        acc += d * d;
    }
    float dr = dinv[r];
    out[(size_t)r * EMB + 1] = dr * dr * acc;
}

// ---- degree counting sort: histogram -> scan -> scatter (perf-only permutation) ----
__global__ void hist_kernel(const int* __restrict__ deg, int* __restrict__ hist) {
    int r = blockIdx.x * 256 + threadIdx.x;
    if (r < NN) atomicAdd(&hist[min(deg[r], 255)], 1);
}

__global__ void histscan_kernel(const int* __restrict__ hist, int* __restrict__ binofs) {
    __shared__ int wsum[4];
    int tid = threadIdx.x;            // 256 threads
    int lane = tid & 63, wid = tid >> 6;
    int v = hist[tid];
    int s = v;
#pragma unroll
    for (int d = 1; d < 64; d <<= 1) {
        int t = __shfl_up(s, d);
        if (lane >= d) s += t;
    }
    if (lane == 63) wsum[wid] = s;
    __syncthreads();
    int ofs = 0;
    for (int w = 0; w < wid; ++w) ofs += wsum[w];
    binofs[tid] = ofs + s - v;
}

__global__ void permute_kernel(const int* __restrict__ deg, int* __restrict__ binofs,
                               int* __restrict__ perm) {
    int r = blockIdx.x * 256 + threadIdx.x;
    if (r < NN) {
        int pos = atomicAdd(&binofs[min(deg[r], 255)], 1);
        perm[pos] = r;
    }
}

// block per row: zero the row then scatter S values (fused memset+init)
__global__ void init_w1(const int* __restrict__ rowptr, const unsigned* __restrict__ cpk,
                        _Float16* __restrict__ W1, int c0, int B) {
    int r = blockIdx.x;
    _Float16* wr = W1 + (size_t)r * B;
    half8 z = {0, 0, 0, 0, 0, 0, 0, 0};
    for (int i = threadIdx.x; i < (B >> 3); i += 256) ((half8*)wr)[i] = z;
    __syncthreads();
    int s = rowptr[r], e = rowptr[r + 1];
    for (int p = s + (int)threadIdx.x; p < e; p += 256) {
        unsigned w = cpk[p];
        unsigned j = (w & 0xffffu) - (unsigned)c0;
        if (j < (unsigned)B) ((unsigned short*)wr)[j] = (unsigned short)(w >> 16);
    }
}

// Wnxt[r, grp cols] = sum_{c in N(r)} S_rc * Win[c, grp cols]  (v_fma_mix, u32 saddr offs).
// Rows taken via degree-sorted perm -> all rows in a block have ~equal nnz.
// Fused: dot_j += W_m[r,j]*Wnxt[r,j], nrm_j += Wnxt[r,j]^2 -> block partial.
// PLAIN panel store (keeps next dispatch's gathers L2/L3-served).
__global__ __launch_bounds__(512) void
spmm_fused(const int* __restrict__ rowptr, const unsigned* __restrict__ cpk,
           const int* __restrict__ perm, const _Float16* __restrict__ Win,
           _Float16* __restrict__ Wout, float* __restrict__ partial,
           int bsh /*log2(B)*/, int SUBS) {
    int i = blockIdx.x;
    int xcd = i & 7;
    int q = i >> 3;
    int sub = q / NRB;
    int rblk = q - sub * NRB;
    int grp = xcd * SUBS + sub;
    int tid = threadIdx.x;
    int lane = tid & (TPR - 1);
    int r = perm[rblk * RPB + (tid >> 4)];
    int j = grp * GCOLS + lane * 8;
    const char* Wc = (const char*)Win;
    unsigned jb = (unsigned)(j * 2);
    int sh = bsh + 1;
    int p = rowptr[r], e = rowptr[r + 1];
    float acc[8] = {0.f, 0.f, 0.f, 0.f, 0.f, 0.f, 0.f, 0.f};
    for (; p + 4 <= e; p += 4) {
        unsigned w0 = cpk[p], w1 = cpk[p + 1], w2 = cpk[p + 2], w3 = cpk[p + 3];
        half8 s0 = *(const half8*)(Wc + (((w0 & 0xffffu) << sh) + jb));
        half8 s1 = *(const half8*)(Wc + (((w1 & 0xffffu) << sh) + jb));
        half8 s2 = *(const half8*)(Wc + (((w2 & 0xffffu) << sh) + jb));
        half8 s3 = *(const half8*)(Wc + (((w3 & 0xffffu) << sh) + jb));
        half2t v0 = __builtin_bit_cast(half2t, w0);
        half2t v1 = __builtin_bit_cast(half2t, w1);
        half2t v2 = __builtin_bit_cast(half2t, w2);
        half2t v3 = __builtin_bit_cast(half2t, w3);
#pragma unroll
        for (int k = 0; k < 8; ++k) {
            acc[k] = fmaf((float)s0[k], (float)v0[1], acc[k]);   // v_fma_mix_f32
            acc[k] = fmaf((float)s1[k], (float)v1[1], acc[k]);
            acc[k] = fmaf((float)s2[k], (float)v2[1], acc[k]);
            acc[k] = fmaf((float)s3[k], (float)v3[1], acc[k]);
        }
    }
    for (; p < e; ++p) {
        unsigned w0 = cpk[p];
        half8 s0 = *(const half8*)(Wc + (((w0 & 0xffffu) << sh) + jb));
        half2t v0 = __builtin_bit_cast(half2t, w0);
#pragma unroll
        for (int k = 0; k < 8; ++k) acc[k] = fmaf((float)s0[k], (float)v0[1], acc[k]);
    }
    union { half8 h; u32x4 u; } o;
#pragma unroll
    for (int k = 0; k < 8; ++k) o.h[k] = (_Float16)acc[k];
    *(u32x4*)(Wout + (((size_t)r << bsh)) + j) = o.u;        // plain store

    // fused reductions: a = W_m[r, j..j+8] is an L2-hit inside the resident slice
    half8 a = *(const half8*)(Win + ((size_t)r << bsh) + j);
    float d[8], n[8];
#pragma unroll
    for (int k = 0; k < 8; ++k) {
        float b = acc[k];
        d[k] = (float)a[k] * b;
        n[k] = b * b;
    }
#pragma unroll
    for (int k = 0; k < 8; ++k) {            // reduce the 4 rows within a wave
        d[k] += __shfl_xor(d[k], 16);
        d[k] += __shfl_xor(d[k], 32);
        n[k] += __shfl_xor(n[k], 16);
        n[k] += __shfl_xor(n[k], 32);
    }
    __shared__ float red[8][2][8][17];       // [wave][dot/nrm][k][lane16] (+1 pad: no conflicts)
    int wv = tid >> 6;
    int l64 = tid & 63;
    if (l64 < 16) {
#pragma unroll
        for (int k = 0; k < 8; ++k) {
            red[wv][0][k][l64] = d[k];
            red[wv][1][k][l64] = n[k];
        }
    }
    __syncthreads();
    if (tid < 2 * GCOLS) {
        int which = tid >> 7;
        int col = tid & (GCOLS - 1);         // col = l16*8 + k
        float s = 0.f;
#pragma unroll
        for (int w = 0; w < 8; ++w) s += red[w][which][col & 7][col >> 3];
        partial[(((size_t)(rblk * 2 + which)) << bsh) + grp * GCOLS + col] = s;
    }
}

// out[(c0+col)*EMB + t] += partial sums; grid (B/256, NRB/16), atomicAdd into zeroed slots.
__global__ void reduce_final(const float* __restrict__ partial, float* __restrict__ out,
                             int c0, int bsh, int tdot, int tnorm) {
    int col = blockIdx.x * 256 + threadIdx.x;
    int rb0 = blockIdx.y * 16;
    float ds = 0.f, ns = 0.f;
    for (int rb = rb0; rb < rb0 + 16; ++rb) {
        ds += partial[((size_t)(rb * 2 + 0) << bsh) + col];
        ns += partial[((size_t)(rb * 2 + 1) << bsh) + col];
    }
    atomicAdd(out + (size_t)(c0 + col) * EMB + tdot, ds);
    atomicAdd(out + (size_t)(c0 + col) * EMB + tnorm, ns);
}

extern "C" void kernel_launch(void* const* d_in, const int* in_sizes, int n_in,
                              void* d_out, int out_size, void* d_ws, size_t ws_size,
                              hipStream_t stream) {
    const int* ei = (const int*)d_in[1];     // edge_index [2, nE]
    int nE = in_sizes[1] / 2;                // 131072
    float* out = (float*)d_out;

    char* ws = (char*)d_ws;
    size_t off = 0;
    auto alloc = [&](size_t bytes) -> void* {
        void* p = ws + off;
        off = (off + bytes + 255) & ~(size_t)255;
        return p;
    };
    unsigned* bm  = (unsigned*)alloc((size_t)NN * NWORDS * 4);   // 8 MB bitmap
    int*      deg = (int*)alloc((size_t)NN * 4);
    float*   dinv = (float*)alloc((size_t)NN * 4);
    int*   rowptr = (int*)alloc((size_t)(NN + 1) * 4);
    size_t maxnnz = 2 * (size_t)nE;
    unsigned* cpk = (unsigned*)alloc(maxnnz * 4);
    int*     hist = (int*)alloc(256 * 4);
    int*   binofs = (int*)alloc(256 * 4);
    int*     perm = (int*)alloc((size_t)NN * 4);
    size_t fixed = off;

    // column width: prefer one pass (B=8192); pair + partials must fit workspace.
    int B = 8192, bsh = 13;
    while (B > 2048 &&
           fixed + 2 * (size_t)NN * B * 2 + (size_t)NRB * 2 * B * 4 > ws_size) {
        B >>= 1; bsh--;
    }
    _Float16* Wa = (_Float16*)alloc((size_t)NN * B * 2);
    _Float16* Wb = (_Float16*)alloc((size_t)NN * B * 2);
    float* partial = (float*)alloc((size_t)NRB * 2 * B * 4);
    int SUBS = (B / GCOLS) / 8;              // col-group slices per XCD

    (void)hipMemsetAsync(d_out, 0, (size_t)out_size * 4, stream);
    (void)hipMemsetAsync(bm, 0, (size_t)NN * NWORDS * 4, stream);
    (void)hipMemsetAsync(hist, 0, 256 * 4, stream);

    scatter_edges<<<(nE + 255) / 256, 256, 0, stream>>>(ei, bm, nE);
    degree_kernel<<<NN / 4, 256, 0, stream>>>(bm, deg, dinv, out);
    scan_kernel<<<1, 256, 0, stream>>>(deg, rowptr);
    fill_cpk<<<NN / 256, 256, 0, stream>>>(bm, rowptr, dinv, cpk);
    diag2_kernel<<<NN / 256, 256, 0, stream>>>(rowptr, cpk, dinv, out);
    hist_kernel<<<NN / 256, 256, 0, stream>>>(deg, hist);
    histscan_kernel<<<1, 256, 0, stream>>>(hist, binofs);
    permute_kernel<<<NN / 256, 256, 0, stream>>>(deg, binofs, perm);

    dim3 spmm_grid(8 * SUBS * NRB);
    dim3 fin_grid(B / 256, NRB / 16);

    for (int c0 = 0; c0 < NN; c0 += B) {
        init_w1<<<NN, 256, 0, stream>>>(rowptr, cpk, Wa, c0, B);
        _Float16* cur = Wa;
        _Float16* nxt = Wb;
        for (int m = 1; m <= 4; ++m) {
            spmm_fused<<<spmm_grid, 512, 0, stream>>>(rowptr, cpk, perm, cur, nxt,
                                                      partial, bsh, SUBS);
            // k=2m+1 (slot 2m): <W_m,W_{m+1}>;  k=2m+2 (slot 2m+1): ||W_{m+1}||^2
            reduce_final<<<fin_grid, 256, 0, stream>>>(partial, out, c0, bsh, 2 * m, 2 * m + 1);
            _Float16* t = cur; cur = nxt; nxt = t;
        }
    }
}